// Round 13
// baseline (430.898 us; speedup 1.0000x reference)
//
#include <hip/hip_runtime.h>
#include <hip/hip_cooperative_groups.h>
#include <stdint.h>

namespace cg = cooperative_groups;

typedef unsigned int u32;
typedef unsigned long long u64;

#define NCLS 80
#define NBOX 22743
#define PREK 4096
#define BCAP 32768
#define NIMG 8
#define SCORE_TH 0.01f
#define IOU_TH 0.45f
#define TOPK 200

// class-chunking: decode = 4 chunks x 20 classes, gather = 8 chunks x 10 classes
#define DCH 20
#define DNCH 4
#define GCH 10
#define GNCH 8

// per-block LDS staging capacity for gather hit lists
#define LCAP 1536

// NMS class-bucket params (round-5 exactness proof)
#define BKCAP 8
#define HCAP 224
#define HUGE_TH 3488.0f

// rank split: 4 j-chunks of 1024 keys
#define RJC 4
#define RJW 1024

// stage-1 coarse score bins: (bits>>17)-7680
#define CBINS 512
#define CBIN_BASE 7680u

// ---- workspace layout (bytes) ----
#define HIST_OFF 0
#define CNT_OFF  16384
#define H2_OFF   18432
#define TIES_OFF 542720
#define ZERO_BYTES 575488
#define WIN_OFF  575488
#define BND_OFF  837632
#define PART_OFF BND_OFF   // overlays boundary (consumed before rank phase)
#define BOX_OFF  2934784
#define SKEY_OFF 5845888
#define SOBOX_OFF 6108032
#define SAREA_OFF 6632320

__device__ __forceinline__ float sigmf(float x) { return 1.0f / (1.0f + expf(-x)); }

__device__ __forceinline__ u64 pad_key(int i) { return (u64)(~(u32)i); }  // below all real keys, distinct

// ---------------- workspace zero-init ----------------
__global__ __launch_bounds__(256) void init_k(uint4* __restrict__ ws) {
  const int i = blockIdx.x * 256 + threadIdx.x;
  if (i < ZERO_BYTES / 16) ws[i] = make_uint4(0u, 0u, 0u, 0u);
}

// ---------------- merged decode + coarse hist (all 3 levels), class-chunked ----------------
__global__ __launch_bounds__(256) void decode_hist_all(const float* __restrict__ in0,
                              const float* __restrict__ in1, const float* __restrict__ in2,
                              float4* __restrict__ boxes, u32* __restrict__ hist) {
  __shared__ u32 lh[CBINS];
  const int img = blockIdx.y;
  const int c0 = blockIdx.z * DCH;
  for (int i = threadIdx.x; i < CBINS; i += 256) lh[i] = 0;
  __syncthreads();

  const int bx = blockIdx.x;
  if (bx < 5) {
    const int W = 19, HW = 361;
    const int r = bx * 256 + threadIdx.x;
    if (r < 3 * HW) {
      const int a = r / HW, p = r - a * HW;
      const int y = p / W, x = p - y * W;
      const float* base = in0 + ((size_t)(img * 255 + a * 85)) * (size_t)HW + p;
      float l[DCH];
#pragma unroll
      for (int k = 0; k < DCH; ++k) l[k] = base[(size_t)(5 + c0 + k) * HW];
      const float x4 = base[4 * (size_t)HW];
      if (c0 == 0) {
        const float aw = (a == 0) ? 3.625f : ((a == 1) ? 4.875f : 11.65625f);
        const float ah = (a == 0) ? 2.8125f : ((a == 1) ? 6.1875f : 10.1875f);
        const float x0 = base[0];
        const float x1 = base[(size_t)HW];
        const float x2 = base[2 * (size_t)HW];
        const float x3 = base[3 * (size_t)HW];
        const float px = sigmf(x0) + (float)x;
        const float py = sigmf(x1) + (float)y;
        const float pw = expf(x2) * aw;
        const float ph = expf(x3) * ah;
        const float cx = px * 32.f, cy = py * 32.f, bw = pw * 32.f, bh = ph * 32.f;
        boxes[(size_t)img * NBOX + r] =
            make_float4(cx - bw * 0.5f, cy - bh * 0.5f, cx + bw * 0.5f, cy + bh * 0.5f);
      }
      const float conf = sigmf(x4);
      if (conf > SCORE_TH) {
#pragma unroll
        for (int k = 0; k < DCH; ++k) {
          float s = conf * sigmf(l[k]);
          if (s > SCORE_TH) {
            u32 bin = (__float_as_uint(s) >> 17) - CBIN_BASE;
            atomicAdd(&lh[bin], 1u);
          }
        }
      }
    }
  } else {
    const bool L1 = bx < 10;
    const float* in = L1 ? in1 : in2;
    const int W = L1 ? 38 : 76;
    const int HW = L1 ? 1444 : 5776;
    const int lvl_off = L1 ? 1083 : 5415;
    const float stride = L1 ? 16.f : 8.f;
    const int HW4 = HW >> 2;
    const int idx = (bx - (L1 ? 5 : 10)) * 256 + threadIdx.x;
    if (idx < 3 * HW4) {
      const int a = idx / HW4;
      const int p0 = (idx - a * HW4) << 2;
      const float* base = in + ((size_t)(img * 255 + a * 85)) * (size_t)HW + p0;
      float4 scv[DCH];
#pragma unroll
      for (int k = 0; k < DCH; ++k)
        scv[k] = *(const float4*)(base + (size_t)(5 + c0 + k) * HW);
      float4 v4 = *(const float4*)(base + 4 * (size_t)HW);
      const float* t4 = (const float*)&v4;
      float conf[4];
      if (c0 == 0) {
        const float aw = L1 ? ((a == 0) ? 1.875f : ((a == 1) ? 3.875f : 3.6875f))
                            : ((a == 0) ? 1.25f : ((a == 1) ? 2.f : 4.125f));
        const float ah = L1 ? ((a == 0) ? 3.8125f : ((a == 1) ? 2.8125f : 7.4375f))
                            : ((a == 0) ? 1.625f : ((a == 1) ? 3.75f : 2.875f));
        float4 v0 = *(const float4*)(base);
        float4 v1 = *(const float4*)(base + (size_t)HW);
        float4 v2 = *(const float4*)(base + 2 * (size_t)HW);
        float4 v3 = *(const float4*)(base + 3 * (size_t)HW);
        const float* t0 = (const float*)&v0;
        const float* t1 = (const float*)&v1;
        const float* t2 = (const float*)&v2;
        const float* t3 = (const float*)&v3;
        float4* bout = boxes + (size_t)img * NBOX + lvl_off + a * HW + p0;
#pragma unroll
        for (int i = 0; i < 4; ++i) {
          const int p = p0 + i;
          const int y = p / W, x = p - y * W;
          const float px = sigmf(t0[i]) + (float)x;
          const float py = sigmf(t1[i]) + (float)y;
          const float pw = expf(t2[i]) * aw;
          const float ph = expf(t3[i]) * ah;
          const float cx = px * stride, cy = py * stride, bw = pw * stride, bh = ph * stride;
          bout[i] = make_float4(cx - bw * 0.5f, cy - bh * 0.5f, cx + bw * 0.5f, cy + bh * 0.5f);
        }
      }
#pragma unroll
      for (int i = 0; i < 4; ++i) conf[i] = sigmf(t4[i]);
#pragma unroll
      for (int k = 0; k < DCH; ++k) {
        const float* s4 = (const float*)&scv[k];
#pragma unroll
        for (int i = 0; i < 4; ++i) {
          float s = conf[i] * sigmf(s4[i]);
          if (s > SCORE_TH) {
            u32 bin = (__float_as_uint(s) >> 17) - CBIN_BASE;
            atomicAdd(&lh[bin], 1u);
          }
        }
      }
    }
  }
  __syncthreads();
  u32* gh = hist + (size_t)img * CBINS;
  for (int i = threadIdx.x; i < CBINS; i += 256) {
    u32 v = lh[i];
    if (v) atomicAdd(&gh[i], v);
  }
}

// ---- block-staged list flush ----
__device__ __forceinline__ void flush_list(const u64* llist, int lcnt, int cap,
                                           int* gctr, u64* glist, int gcap) {
  __shared__ int gbase_s;
  int n = lcnt < cap ? lcnt : cap;
  if (threadIdx.x == 0) gbase_s = n ? atomicAdd(gctr, n) : 0;
  __syncthreads();
  const int gb = gbase_s;
  for (int i = threadIdx.x; i < n; i += 256) {
    int pos = gb + i;
    if (pos < gcap) glist[pos] = llist[i];
  }
}

// ---------------- merged gather with fused coarse boundary-bin scan ----------------
__global__ __launch_bounds__(256) void gather_all(const float* __restrict__ in0,
                         const float* __restrict__ in1, const float* __restrict__ in2,
                         const u32* __restrict__ hist, int* __restrict__ cnt,
                         u64* __restrict__ winners, u64* __restrict__ boundary) {
  __shared__ u64 lwin[LCAP];
  __shared__ u64 lbnd[LCAP];
  __shared__ int lwc, lbc;
  __shared__ u32 s_wsum[4];
  __shared__ int sB;
  const int img = blockIdx.y;
  const int c0 = blockIdx.z * GCH;
  const int t = threadIdx.x;
  if (t == 0) { lwc = 0; lbc = 0; sB = -1; }

  // fused scan over 512 coarse bins
  {
    const u32* gh = hist + (size_t)img * CBINS;
    u32 hv0 = gh[t * 2], hv1 = gh[t * 2 + 1];
    u32 s = hv0 + hv1;
    const int lane = t & 63;
    u32 v = s;
#pragma unroll
    for (int off = 1; off < 64; off <<= 1) {
      u32 o = __shfl_down(v, off);
      if (lane + off < 64) v += o;
    }
    if (lane == 0) s_wsum[t >> 6] = v;
    __syncthreads();
    u32 hi = 0;
    for (int w = (t >> 6) + 1; w < 4; ++w) hi += s_wsum[w];
    const u32 above = hi + (v - s);
    if (above < (u32)PREK && above + s >= (u32)PREK) {
      u32 cum = above + hv1;
      if (cum >= (u32)PREK) sB = t * 2 + 1;
      else sB = t * 2;
    }
    __syncthreads();
  }
  const int B = sB;

  int* cw = &cnt[img * 64];
  int* cb = &cnt[img * 64 + 32];
  u64* wl = winners + (size_t)img * PREK;
  u64* bl = boundary + (size_t)img * BCAP;
  const int bx = blockIdx.x;

  if (bx < 5) {
    const int HW = 361;
    const int r = bx * 256 + t;
    if (r < 3 * HW) {
      const int a = r / HW, p = r - a * HW;
      const float* base = in0 + ((size_t)(img * 255 + a * 85)) * (size_t)HW + p;
      const int boxg = r;
      float l[GCH];
#pragma unroll
      for (int k = 0; k < GCH; ++k) l[k] = base[(size_t)(5 + c0 + k) * HW];
      const float conf = sigmf(base[4 * (size_t)HW]);
#pragma unroll
      for (int k = 0; k < GCH; ++k) {
        float s = conf * sigmf(l[k]);
        if (s > SCORE_TH) {
          u32 key = __float_as_uint(s);
          int wbin = (int)((key >> 17) - CBIN_BASE);
          if (wbin >= B) {
            u64 kv = ((u64)key << 32) | (u64)(~(u32)(boxg * NCLS + (c0 + k)));
            if (wbin > B) {
              int p2 = atomicAdd(&lwc, 1);
              if (p2 < LCAP) lwin[p2] = kv;
              else { int g = atomicAdd(cw, 1); if (g < PREK) wl[g] = kv; }
            } else {
              int p2 = atomicAdd(&lbc, 1);
              if (p2 < LCAP) lbnd[p2] = kv;
              else { int g = atomicAdd(cb, 1); if (g < BCAP) bl[g] = kv; }
            }
          }
        }
      }
    }
  } else {
    const bool L1 = bx < 10;
    const float* in = L1 ? in1 : in2;
    const int HW = L1 ? 1444 : 5776;
    const int lvl_off = L1 ? 1083 : 5415;
    const int HW4 = HW >> 2;
    const int idx = (bx - (L1 ? 5 : 10)) * 256 + t;
    if (idx < 3 * HW4) {
      const int a = idx / HW4;
      const int p0 = (idx - a * HW4) << 2;
      const float* base = in + ((size_t)(img * 255 + a * 85)) * (size_t)HW + p0;
      const int boxg0 = lvl_off + a * HW + p0;
      float4 scv[GCH];
#pragma unroll
      for (int k = 0; k < GCH; ++k)
        scv[k] = *(const float4*)(base + (size_t)(5 + c0 + k) * HW);
      float4 v4 = *(const float4*)(base + 4 * (size_t)HW);
      const float* t4 = (const float*)&v4;
      float conf[4];
#pragma unroll
      for (int i = 0; i < 4; ++i) conf[i] = sigmf(t4[i]);
#pragma unroll
      for (int k = 0; k < GCH; ++k) {
        const float* s4 = (const float*)&scv[k];
        const int c = c0 + k;
#pragma unroll
        for (int i = 0; i < 4; ++i) {
          float s = conf[i] * sigmf(s4[i]);
          if (s > SCORE_TH) {
            u32 key = __float_as_uint(s);
            int wbin = (int)((key >> 17) - CBIN_BASE);
            if (wbin >= B) {
              u64 kv = ((u64)key << 32) | (u64)(~(u32)((boxg0 + i) * NCLS + c));
              if (wbin > B) {
                int p = atomicAdd(&lwc, 1);
                if (p < LCAP) lwin[p] = kv;
                else { int g = atomicAdd(cw, 1); if (g < PREK) wl[g] = kv; }
              } else {
                int p = atomicAdd(&lbc, 1);
                if (p < LCAP) lbnd[p] = kv;
                else { int g = atomicAdd(cb, 1); if (g < BCAP) bl[g] = kv; }
              }
            }
          }
        }
      }
    }
  }
  __syncthreads();
  flush_list(lwin, lwc, LCAP, cw, wl, PREK);
  flush_list(lbnd, lbc, LCAP, cb, bl, BCAP);
}

// ---------------- fused cooperative tail: resolve + rank + sort-scatter + NMS ----------------
struct NmsS {
  float4 bxc[NCLS][BKCAP]; float arc[NCLS][BKCAP]; int cntc[NCLS];
  float4 bxa[TOPK]; float ara[TOPK];
  float4 bxh[HCAP]; float arh[HCAP]; int nhuge;
  float4 chb[64]; float cha[64];
};
struct RankS { u64 lk[RJW]; };
struct CompS { u64 lwin[LCAP]; int lwc; int gbase; };
struct ScanS { u32 lsum[256]; u32 above[256]; u32 total; };
union SU { NmsS n; RankS r; CompS c; ScanS s; };

// cnt row usage: [0]=win cnt, [32]=bnd cnt, [8]=B2, [9]=T2, [10]=tie cnt, [11]=gate
__global__ __launch_bounds__(256) void coop_tail_k(const u64* __restrict__ boundary,
                         int* __restrict__ cnt, u64* __restrict__ winners,
                         int* __restrict__ part, const float4* __restrict__ boxes,
                         u64* __restrict__ skey, float4* __restrict__ sobox,
                         float* __restrict__ sarea, u32* __restrict__ h2g,
                         u64* __restrict__ tiesg, float* __restrict__ out) {
  cg::grid_group grid = cg::this_grid();
  __shared__ SU su;
  const int bid = blockIdx.x;   // [0,512)
  const int t = threadIdx.x;

  // ---- R2: boundary refine histogram (64 blocks/img); pre-modification reads safe ----
  {
    const int img = bid >> 6, sub = bid & 63;
    const int T = PREK - cnt[img * 64];
    int bc = cnt[img * 64 + 32]; if (bc > BCAP) bc = BCAP;
    if (T > 0 && bc > 0) {
      const u64* bnd = boundary + (size_t)img * BCAP;
      u32* h2 = h2g + (size_t)img * 16384;
      for (int i = sub * 256 + t; i < bc; i += 64 * 256)
        atomicAdd(&h2[(u32)(bnd[i] >> 35) & 0x3FFFu], 1u);
    }
  }
  grid.sync();

  // ---- R3: per-image scan of h2 -> B2, T2, gate (8 blocks) ----
  if (bid < 8) {
    const int img = bid;
    const int T = PREK - cnt[img * 64];
    int bc = cnt[img * 64 + 32]; if (bc > BCAP) bc = BCAP;
    const int gate = (T > 0 && bc > 0) ? 1 : 0;
    if (t == 0) { cnt[img * 64 + 8] = -1; cnt[img * 64 + 9] = 0; cnt[img * 64 + 11] = gate; }
    __syncthreads();
    if (gate) {
      const u32* h2 = h2g + (size_t)img * 16384;
      u32 s = 0;
      for (int j = 0; j < 64; ++j) s += h2[t * 64 + j];
      su.s.lsum[t] = s;
      __syncthreads();
      if (t == 0) {
        u32 acc = 0;
        for (int i = 255; i >= 0; --i) { su.s.above[i] = acc; acc += su.s.lsum[i]; }
        su.s.total = acc;
      }
      __syncthreads();
      if ((int)su.s.total > T) {
        if (su.s.above[t] < (u32)T && su.s.above[t] + su.s.lsum[t] >= (u32)T) {
          u32 cum = su.s.above[t];
          for (int j = 63; j >= 0; --j) {
            u32 hv = h2[t * 64 + j];
            cum += hv;
            if (cum >= (u32)T) {
              cnt[img * 64 + 8] = t * 64 + j;
              cnt[img * 64 + 9] = (int)((u32)T - (cum - hv));
              break;
            }
          }
        }
      }
    }
  }
  grid.sync();

  // ---- R4: compact boundary (64 blocks/img, block-staged flush) ----
  {
    const int img = bid >> 6, sub = bid & 63;
    if (cnt[img * 64 + 11]) {
      const int B2 = cnt[img * 64 + 8];
      int bc = cnt[img * 64 + 32]; if (bc > BCAP) bc = BCAP;
      const u64* bnd = boundary + (size_t)img * BCAP;
      u64* wl = winners + (size_t)img * PREK;
      if (t == 0) su.c.lwc = 0;
      __syncthreads();
      for (int i = sub * 256 + t; i < bc; i += 64 * 256) {
        u64 e = bnd[i];
        int low = (int)((u32)(e >> 35) & 0x3FFFu);
        if (low > B2) {
          int p = atomicAdd(&su.c.lwc, 1);
          if (p < LCAP) su.c.lwin[p] = e;
          else { int g = atomicAdd(&cnt[img * 64], 1); if (g < PREK) wl[g] = e; }
        } else if (low == B2) {
          int tp = atomicAdd(&cnt[img * 64 + 10], 1);
          if (tp < 512) tiesg[(size_t)img * 512 + tp] = e;
        }
      }
      __syncthreads();
      int n = su.c.lwc < LCAP ? su.c.lwc : LCAP;
      if (t == 0) su.c.gbase = n ? atomicAdd(&cnt[img * 64], n) : 0;
      __syncthreads();
      for (int i = t; i < n; i += 256) {
        int pos = su.c.gbase + i;
        if (pos < PREK) wl[pos] = su.c.lwin[i];
      }
    }
  }
  grid.sync();

  // ---- R5: ties pick, exact greedy order by full u64 key (8 blocks, t0) ----
  if (bid < 8 && t == 0) {
    const int img = bid;
    if (cnt[img * 64 + 11]) {
      const int T2 = cnt[img * 64 + 9];
      if (T2 > 0) {
        int tc = cnt[img * 64 + 10]; if (tc > 512) tc = 512;
        u64* wl = winners + (size_t)img * PREK;
        u64* ties = tiesg + (size_t)img * 512;
        for (int k = 0; k < T2 && k < tc; ++k) {
          int bi = -1; u64 bk = 0;
          for (int i = 0; i < tc; ++i)
            if (ties[i] > bk) { bk = ties[i]; bi = i; }
          if (bi < 0) break;
          ties[bi] = 0;
          int pos = atomicAdd(&cnt[img * 64], 1);
          if (pos < PREK) wl[pos] = bk;
        }
      }
    }
  }
  grid.sync();

  // ---- R6: rank partials (all 512 blocks; part overlays boundary — done with it) ----
  {
    const int img = bid >> 6, x = bid & 63;
    const int kc = x >> 2, jc = x & 3;
    int wc = cnt[img * 64]; if (wc > PREK) wc = PREK;
    const u64* wl = winners + (size_t)img * PREK;
    for (int i = t; i < RJW; i += 256) {
      const int gj = jc * RJW + i;
      su.r.lk[i] = (gj < wc) ? wl[gj] : pad_key(gj);
    }
    __syncthreads();
    const int ki_idx = kc * 256 + t;
    const u64 ki = (ki_idx < wc) ? wl[ki_idx] : pad_key(ki_idx);
    int rank = 0;
#pragma unroll 8
    for (int j = 0; j < RJW; ++j) rank += (su.r.lk[j] > ki) ? 1 : 0;
    part[(((size_t)img * RJC) + jc) * PREK + ki_idx] = rank;
  }
  grid.sync();

  // ---- R7: rank scatter (128 blocks) ----
  if (bid < 128) {
    const int img = bid >> 4, x = bid & 15;
    const int i = x * 256 + t;
    int wc = cnt[img * 64]; if (wc > PREK) wc = PREK;
    const u64* wl = winners + (size_t)img * PREK;
    const u64 ki = (i < wc) ? wl[i] : pad_key(i);
    const int* pb = part + (size_t)img * RJC * PREK + i;
    int rank = pb[0] + pb[PREK] + pb[2 * PREK] + pb[3 * PREK];
    skey[(size_t)img * PREK + rank] = ki;
    if (i < wc) {
      u32 ridx = ~(u32)ki;
      int c = (int)(ridx % NCLS);
      int bi = (int)(ridx / NCLS);
      float4 b = boxes[(size_t)img * NBOX + bi];
      float off = 4096.0f * (float)c;
      float4 ob = make_float4(b.x + off, b.y + off, b.z + off, b.w + off);
      sobox[(size_t)img * PREK + rank] = ob;
      sarea[(size_t)img * PREK + rank] = (ob.z - ob.x) * (ob.w - ob.y);
    } else {
      sobox[(size_t)img * PREK + rank] = make_float4(0.f, 0.f, 0.f, 0.f);
      sarea[(size_t)img * PREK + rank] = 0.f;
    }
  }
  grid.sync();

  // ---- R8: sorted-scan greedy NMS (8 blocks, wave 0) ----
  if (bid < 8 && t < 64) {
    const int img = bid;
    const int lane = t;
    float* orow = out + (size_t)img * (TOPK * 6);
    for (int i = lane; i < TOPK * 6; i += 64) orow[i] = 0.f;
    for (int i = lane; i < NCLS; i += 64) su.n.cntc[i] = 0;
    if (lane == 0) su.n.nhuge = 0;
    const u64* K = skey + (size_t)img * PREK;
    const float4* Bp = sobox + (size_t)img * PREK;
    const float* Ap = sarea + (size_t)img * PREK;
    int nsel = 0;
    u64 kj = K[lane];
    float4 ob = Bp[lane];
    float ar = Ap[lane];
    for (int chunk = 0; chunk < PREK / 64 && nsel < TOPK; ++chunk) {
      u64 kj_n = 0ull; float4 ob_n = make_float4(0.f, 0.f, 0.f, 0.f); float ar_n = 0.f;
      if (chunk + 1 < PREK / 64) {
        const int jn = (chunk + 1) * 64 + lane;
        kj_n = K[jn]; ob_n = Bp[jn]; ar_n = Ap[jn];
      }
      const float score = __uint_as_float((u32)(kj >> 32));
      bool alive = (score > SCORE_TH);
      if (__ballot(alive) == 0ull) break;
      const u32 ridx = ~(u32)kj;
      const int myc = (int)(ridx % NCLS);
      const bool huge = (ob.z - ob.x > HUGE_TH) || (ob.w - ob.y > HUGE_TH);
      su.n.chb[lane] = ob; su.n.cha[lane] = ar;

      u64 mm = ~0ull;
#pragma unroll
      for (int k = 0; k < 7; ++k) {
        const u64 bk = __ballot(((myc >> k) & 1) != 0);
        mm &= (((myc >> k) & 1) != 0) ? bk : ~bk;
      }
      const u64 hb = __ballot(huge);

      {
        const int n0 = su.n.cntc[myc];
        const int n = n0 < BKCAP ? n0 : BKCAP;
        for (int k = 0; k < n && alive; ++k) {
          const float4 b0 = su.n.bxc[myc][k]; const float a0 = su.n.arc[myc][k];
          float xx1 = fmaxf(b0.x, ob.x), yy1 = fmaxf(b0.y, ob.y);
          float xx2 = fminf(b0.z, ob.z), yy2 = fminf(b0.w, ob.w);
          float inter = fmaxf(xx2 - xx1, 0.f) * fmaxf(yy2 - yy1, 0.f);
          float iou = inter / (a0 + ar - inter + 1e-9f);
          if (iou > IOU_TH) alive = false;
        }
      }
      {
        const int nh = su.n.nhuge;
        for (int k = 0; k < nh; ++k) {
          if (alive) {
            const float4 b0 = su.n.bxh[k]; const float a0 = su.n.arh[k];
            float xx1 = fmaxf(b0.x, ob.x), yy1 = fmaxf(b0.y, ob.y);
            float xx2 = fminf(b0.z, ob.z), yy2 = fminf(b0.w, ob.w);
            float inter = fmaxf(xx2 - xx1, 0.f) * fmaxf(yy2 - yy1, 0.f);
            float iou = inter / (a0 + ar - inter + 1e-9f);
            if (iou > IOU_TH) alive = false;
          }
        }
      }
      if (__ballot(alive && huge) != 0ull) {
        const int na = nsel;
        for (int k = 0; k < na; ++k) {
          if (alive && huge) {
            const float4 b0 = su.n.bxa[k]; const float a0 = su.n.ara[k];
            float xx1 = fmaxf(b0.x, ob.x), yy1 = fmaxf(b0.y, ob.y);
            float xx2 = fminf(b0.z, ob.z), yy2 = fminf(b0.w, ob.w);
            float inter = fmaxf(xx2 - xx1, 0.f) * fmaxf(yy2 - yy1, 0.f);
            float iou = inter / (a0 + ar - inter + 1e-9f);
            if (iou > IOU_TH) alive = false;
          }
        }
      }
      const u64 amask = __ballot(alive);
      const u64 below = (1ull << lane) - 1ull;
      u64 tm = alive ? ((mm | hb | (huge ? ~0ull : 0ull)) & below & amask) : 0ull;
      u64 sup = 0ull;
      while (tm) {
        const int tb = (int)__builtin_ctzll(tm);
        tm &= tm - 1ull;
        const float4 bj = su.n.chb[tb];
        const float aj = su.n.cha[tb];
        float xx1 = fmaxf(bj.x, ob.x), yy1 = fmaxf(bj.y, ob.y);
        float xx2 = fminf(bj.z, ob.z), yy2 = fminf(bj.w, ob.w);
        float inter = fmaxf(xx2 - xx1, 0.f) * fmaxf(yy2 - yy1, 0.f);
        float iou = inter / (aj + ar - inter + 1e-9f);
        if (iou > IOU_TH) sup |= (1ull << tb);
      }
      u64 rem = amask;
      u64 selbits = 0ull;
      while (rem != 0ull && nsel + (int)__popcll(selbits) < TOPK) {
        const int b = __builtin_ctzll(rem);
        selbits |= (1ull << b);
        rem &= ~(1ull << b);
        const u64 colb = __ballot((sup >> b) & 1ull);
        rem &= ~colb;
      }
      const bool selme = (selbits >> lane) & 1ull;
      if (selme) {
        const int slot = nsel + (int)__popcll(selbits & ((1ull << lane) - 1ull));
        su.n.bxa[slot] = ob; su.n.ara[slot] = ar;
        if (!huge) {
          int cc = atomicAdd(&su.n.cntc[myc], 1);
          if (cc < BKCAP) { su.n.bxc[myc][cc] = ob; su.n.arc[myc][cc] = ar; }
          else { int hn = atomicAdd(&su.n.nhuge, 1); if (hn < HCAP) { su.n.bxh[hn] = ob; su.n.arh[hn] = ar; } }
        } else {
          int hn = atomicAdd(&su.n.nhuge, 1);
          if (hn < HCAP) { su.n.bxh[hn] = ob; su.n.arh[hn] = ar; }
        }
        const float off = 4096.0f * (float)myc;
        orow[slot * 6 + 0] = ob.x - off;
        orow[slot * 6 + 1] = ob.y - off;
        orow[slot * 6 + 2] = ob.z - off;
        orow[slot * 6 + 3] = ob.w - off;
        orow[slot * 6 + 4] = (float)myc;
        orow[slot * 6 + 5] = score;
      }
      nsel += (int)__popcll(selbits);
      kj = kj_n; ob = ob_n; ar = ar_n;
    }
  }
}

extern "C" void kernel_launch(void* const* d_in, const int* in_sizes, int n_in,
                              void* d_out, int out_size, void* d_ws, size_t ws_size,
                              hipStream_t stream) {
  const float* in0 = (const float*)d_in[0];
  const float* in1 = (const float*)d_in[5];
  const float* in2 = (const float*)d_in[10];
  char* ws = (char*)d_ws;
  u32* hist = (u32*)(ws + HIST_OFF);
  int* cnt = (int*)(ws + CNT_OFF);
  u32* h2g = (u32*)(ws + H2_OFF);
  u64* tiesg = (u64*)(ws + TIES_OFF);
  u64* winners = (u64*)(ws + WIN_OFF);
  u64* boundary = (u64*)(ws + BND_OFF);
  int* part = (int*)(ws + PART_OFF);   // overlays boundary (safe: ordered by grid.sync)
  float4* boxes = (float4*)(ws + BOX_OFF);
  u64* skey = (u64*)(ws + SKEY_OFF);
  float4* sobox = (float4*)(ws + SOBOX_OFF);
  float* sarea = (float*)(ws + SAREA_OFF);
  float* out = (float*)d_out;

  init_k<<<(ZERO_BYTES / 16 + 255) / 256, 256, 0, stream>>>((uint4*)ws);

  decode_hist_all<<<dim3(27, 8, DNCH), 256, 0, stream>>>(in0, in1, in2, boxes, hist);

  gather_all<<<dim3(27, 8, GNCH), 256, 0, stream>>>(in0, in1, in2, hist, cnt, winners, boundary);

  void* args[] = {(void*)&boundary, (void*)&cnt, (void*)&winners, (void*)&part,
                  (void*)&boxes, (void*)&skey, (void*)&sobox, (void*)&sarea,
                  (void*)&h2g, (void*)&tiesg, (void*)&out};
  hipLaunchCooperativeKernel((const void*)coop_tail_k, dim3(512), dim3(256), args, 0, stream);
}

// Round 14
// 113.455 us; speedup vs baseline: 3.7980x; 3.7980x over previous
//
#include <hip/hip_runtime.h>
#include <stdint.h>

typedef unsigned int u32;
typedef unsigned long long u64;

#define NCLS 80
#define NBOX 22743
#define PREK 4096
#define BCAP 32768
#define NIMG 8
#define SCORE_TH 0.01f
#define IOU_TH 0.45f
#define TOPK 200

// class-chunking: decode = 4 chunks x 20 classes, gather = 8 chunks x 10 classes
#define DCH 20
#define DNCH 4
#define GCH 10
#define GNCH 8

// per-block LDS staging capacity for gather hit lists
#define LCAP 1536

// NMS class-bucket params (round-5 exactness proof)
#define BKCAP 8
#define HCAP 224
#define HUGE_TH 3488.0f

// rank split: 4 j-chunks of 1024 keys
#define RJC 4
#define RJW 1024

// stage-1 coarse score bins: (bits>>17)-7680; s in (0.01,1] -> [17,384]
#define CBINS 512
#define CBIN_BASE 7680u

// ---- workspace layout (bytes) ----
#define HIST_OFF 0
#define CNT_OFF  16384
#define ZERO_BYTES 18432
#define WIN_OFF  18432
#define BND_OFF  280576
#define PART_OFF BND_OFF   // overlays boundary (consumed before rank phase)
#define BOX_OFF  2377728
#define SKEY_OFF 5288832
#define SOBOX_OFF 5550976
#define SAREA_OFF 6075264

__device__ __forceinline__ float sigmf(float x) { return 1.0f / (1.0f + expf(-x)); }

__device__ __forceinline__ u64 pad_key(int i) { return (u64)(~(u32)i); }  // below all real keys, distinct

// ---------------- workspace zero-init ----------------
__global__ __launch_bounds__(256) void init_k(uint4* __restrict__ ws) {
  const int i = blockIdx.x * 256 + threadIdx.x;
  if (i < ZERO_BYTES / 16) ws[i] = make_uint4(0u, 0u, 0u, 0u);
}

// ---------------- merged decode + coarse hist (all 3 levels), class-chunked ----------------
// blockIdx.x: [0,5) lvl0 scalar | [5,10) lvl1 v4 | [10,27) lvl2 v4
__global__ __launch_bounds__(256) void decode_hist_all(const float* __restrict__ in0,
                              const float* __restrict__ in1, const float* __restrict__ in2,
                              float4* __restrict__ boxes, u32* __restrict__ hist) {
  __shared__ u32 lh[CBINS];
  const int img = blockIdx.y;
  const int c0 = blockIdx.z * DCH;
  for (int i = threadIdx.x; i < CBINS; i += 256) lh[i] = 0;
  __syncthreads();

  const int bx = blockIdx.x;
  if (bx < 5) {
    const int W = 19, HW = 361;
    const int r = bx * 256 + threadIdx.x;
    if (r < 3 * HW) {
      const int a = r / HW, p = r - a * HW;
      const int y = p / W, x = p - y * W;
      const float* base = in0 + ((size_t)(img * 255 + a * 85)) * (size_t)HW + p;
      float l[DCH];
#pragma unroll
      for (int k = 0; k < DCH; ++k) l[k] = base[(size_t)(5 + c0 + k) * HW];
      const float x4 = base[4 * (size_t)HW];
      if (c0 == 0) {
        const float aw = (a == 0) ? 3.625f : ((a == 1) ? 4.875f : 11.65625f);
        const float ah = (a == 0) ? 2.8125f : ((a == 1) ? 6.1875f : 10.1875f);
        const float x0 = base[0];
        const float x1 = base[(size_t)HW];
        const float x2 = base[2 * (size_t)HW];
        const float x3 = base[3 * (size_t)HW];
        const float px = sigmf(x0) + (float)x;
        const float py = sigmf(x1) + (float)y;
        const float pw = expf(x2) * aw;
        const float ph = expf(x3) * ah;
        const float cx = px * 32.f, cy = py * 32.f, bw = pw * 32.f, bh = ph * 32.f;
        boxes[(size_t)img * NBOX + r] =
            make_float4(cx - bw * 0.5f, cy - bh * 0.5f, cx + bw * 0.5f, cy + bh * 0.5f);
      }
      const float conf = sigmf(x4);
      if (conf > SCORE_TH) {
#pragma unroll
        for (int k = 0; k < DCH; ++k) {
          float s = conf * sigmf(l[k]);
          if (s > SCORE_TH) {
            u32 bin = (__float_as_uint(s) >> 17) - CBIN_BASE;
            atomicAdd(&lh[bin], 1u);
          }
        }
      }
    }
  } else {
    const bool L1 = bx < 10;
    const float* in = L1 ? in1 : in2;
    const int W = L1 ? 38 : 76;
    const int HW = L1 ? 1444 : 5776;
    const int lvl_off = L1 ? 1083 : 5415;
    const float stride = L1 ? 16.f : 8.f;
    const int HW4 = HW >> 2;
    const int idx = (bx - (L1 ? 5 : 10)) * 256 + threadIdx.x;
    if (idx < 3 * HW4) {
      const int a = idx / HW4;
      const int p0 = (idx - a * HW4) << 2;
      const float* base = in + ((size_t)(img * 255 + a * 85)) * (size_t)HW + p0;
      float4 scv[DCH];
#pragma unroll
      for (int k = 0; k < DCH; ++k)
        scv[k] = *(const float4*)(base + (size_t)(5 + c0 + k) * HW);
      float4 v4 = *(const float4*)(base + 4 * (size_t)HW);
      const float* t4 = (const float*)&v4;
      float conf[4];
      if (c0 == 0) {
        const float aw = L1 ? ((a == 0) ? 1.875f : ((a == 1) ? 3.875f : 3.6875f))
                            : ((a == 0) ? 1.25f : ((a == 1) ? 2.f : 4.125f));
        const float ah = L1 ? ((a == 0) ? 3.8125f : ((a == 1) ? 2.8125f : 7.4375f))
                            : ((a == 0) ? 1.625f : ((a == 1) ? 3.75f : 2.875f));
        float4 v0 = *(const float4*)(base);
        float4 v1 = *(const float4*)(base + (size_t)HW);
        float4 v2 = *(const float4*)(base + 2 * (size_t)HW);
        float4 v3 = *(const float4*)(base + 3 * (size_t)HW);
        const float* t0 = (const float*)&v0;
        const float* t1 = (const float*)&v1;
        const float* t2 = (const float*)&v2;
        const float* t3 = (const float*)&v3;
        float4* bout = boxes + (size_t)img * NBOX + lvl_off + a * HW + p0;
#pragma unroll
        for (int i = 0; i < 4; ++i) {
          const int p = p0 + i;
          const int y = p / W, x = p - y * W;
          const float px = sigmf(t0[i]) + (float)x;
          const float py = sigmf(t1[i]) + (float)y;
          const float pw = expf(t2[i]) * aw;
          const float ph = expf(t3[i]) * ah;
          const float cx = px * stride, cy = py * stride, bw = pw * stride, bh = ph * stride;
          bout[i] = make_float4(cx - bw * 0.5f, cy - bh * 0.5f, cx + bw * 0.5f, cy + bh * 0.5f);
        }
      }
#pragma unroll
      for (int i = 0; i < 4; ++i) conf[i] = sigmf(t4[i]);
#pragma unroll
      for (int k = 0; k < DCH; ++k) {
        const float* s4 = (const float*)&scv[k];
#pragma unroll
        for (int i = 0; i < 4; ++i) {
          float s = conf[i] * sigmf(s4[i]);
          if (s > SCORE_TH) {
            u32 bin = (__float_as_uint(s) >> 17) - CBIN_BASE;
            atomicAdd(&lh[bin], 1u);
          }
        }
      }
    }
  }
  __syncthreads();
  u32* gh = hist + (size_t)img * CBINS;
  for (int i = threadIdx.x; i < CBINS; i += 256) {
    u32 v = lh[i];
    if (v) atomicAdd(&gh[i], v);
  }
}

// ---- block-staged list flush: one global atomic per list per block ----
__device__ __forceinline__ void flush_list(const u64* llist, int lcnt, int cap,
                                           int* gctr, u64* glist, int gcap) {
  __shared__ int gbase_s;
  int n = lcnt < cap ? lcnt : cap;
  if (threadIdx.x == 0) gbase_s = n ? atomicAdd(gctr, n) : 0;
  __syncthreads();
  const int gb = gbase_s;
  for (int i = threadIdx.x; i < n; i += 256) {
    int pos = gb + i;
    if (pos < gcap) glist[pos] = llist[i];
  }
}

// ---------------- merged gather with fused coarse boundary-bin scan ----------------
__global__ __launch_bounds__(256) void gather_all(const float* __restrict__ in0,
                         const float* __restrict__ in1, const float* __restrict__ in2,
                         const u32* __restrict__ hist, int* __restrict__ cnt,
                         u64* __restrict__ winners, u64* __restrict__ boundary) {
  __shared__ u64 lwin[LCAP];
  __shared__ u64 lbnd[LCAP];
  __shared__ int lwc, lbc;
  __shared__ u32 s_wsum[4];
  __shared__ int sB;
  const int img = blockIdx.y;
  const int c0 = blockIdx.z * GCH;
  const int t = threadIdx.x;
  if (t == 0) { lwc = 0; lbc = 0; sB = -1; }

  // fused scan over 512 coarse bins: B = boundary bin (suffix count crosses PREK)
  {
    const u32* gh = hist + (size_t)img * CBINS;
    u32 hv0 = gh[t * 2], hv1 = gh[t * 2 + 1];
    u32 s = hv0 + hv1;
    const int lane = t & 63;
    u32 v = s;
#pragma unroll
    for (int off = 1; off < 64; off <<= 1) {
      u32 o = __shfl_down(v, off);
      if (lane + off < 64) v += o;
    }
    if (lane == 0) s_wsum[t >> 6] = v;
    __syncthreads();
    u32 hi = 0;
    for (int w = (t >> 6) + 1; w < 4; ++w) hi += s_wsum[w];
    const u32 above = hi + (v - s);
    if (above < (u32)PREK && above + s >= (u32)PREK) {
      u32 cum = above + hv1;
      if (cum >= (u32)PREK) sB = t * 2 + 1;
      else sB = t * 2;
    }
    __syncthreads();
  }
  const int B = sB;

  int* cw = &cnt[img * 64];
  int* cb = &cnt[img * 64 + 32];
  u64* wl = winners + (size_t)img * PREK;
  u64* bl = boundary + (size_t)img * BCAP;
  const int bx = blockIdx.x;

  if (bx < 5) {
    const int HW = 361;
    const int r = bx * 256 + t;
    if (r < 3 * HW) {
      const int a = r / HW, p = r - a * HW;
      const float* base = in0 + ((size_t)(img * 255 + a * 85)) * (size_t)HW + p;
      const int boxg = r;
      float l[GCH];
#pragma unroll
      for (int k = 0; k < GCH; ++k) l[k] = base[(size_t)(5 + c0 + k) * HW];
      const float conf = sigmf(base[4 * (size_t)HW]);
#pragma unroll
      for (int k = 0; k < GCH; ++k) {
        float s = conf * sigmf(l[k]);
        if (s > SCORE_TH) {
          u32 key = __float_as_uint(s);
          int wbin = (int)((key >> 17) - CBIN_BASE);
          if (wbin >= B) {
            u64 kv = ((u64)key << 32) | (u64)(~(u32)(boxg * NCLS + (c0 + k)));
            if (wbin > B) {
              int p2 = atomicAdd(&lwc, 1);
              if (p2 < LCAP) lwin[p2] = kv;
              else { int g = atomicAdd(cw, 1); if (g < PREK) wl[g] = kv; }
            } else {
              int p2 = atomicAdd(&lbc, 1);
              if (p2 < LCAP) lbnd[p2] = kv;
              else { int g = atomicAdd(cb, 1); if (g < BCAP) bl[g] = kv; }
            }
          }
        }
      }
    }
  } else {
    const bool L1 = bx < 10;
    const float* in = L1 ? in1 : in2;
    const int HW = L1 ? 1444 : 5776;
    const int lvl_off = L1 ? 1083 : 5415;
    const int HW4 = HW >> 2;
    const int idx = (bx - (L1 ? 5 : 10)) * 256 + t;
    if (idx < 3 * HW4) {
      const int a = idx / HW4;
      const int p0 = (idx - a * HW4) << 2;
      const float* base = in + ((size_t)(img * 255 + a * 85)) * (size_t)HW + p0;
      const int boxg0 = lvl_off + a * HW + p0;
      float4 scv[GCH];
#pragma unroll
      for (int k = 0; k < GCH; ++k)
        scv[k] = *(const float4*)(base + (size_t)(5 + c0 + k) * HW);
      float4 v4 = *(const float4*)(base + 4 * (size_t)HW);
      const float* t4 = (const float*)&v4;
      float conf[4];
#pragma unroll
      for (int i = 0; i < 4; ++i) conf[i] = sigmf(t4[i]);
#pragma unroll
      for (int k = 0; k < GCH; ++k) {
        const float* s4 = (const float*)&scv[k];
        const int c = c0 + k;
#pragma unroll
        for (int i = 0; i < 4; ++i) {
          float s = conf[i] * sigmf(s4[i]);
          if (s > SCORE_TH) {
            u32 key = __float_as_uint(s);
            int wbin = (int)((key >> 17) - CBIN_BASE);
            if (wbin >= B) {
              u64 kv = ((u64)key << 32) | (u64)(~(u32)((boxg0 + i) * NCLS + c));
              if (wbin > B) {
                int p = atomicAdd(&lwc, 1);
                if (p < LCAP) lwin[p] = kv;
                else { int g = atomicAdd(cw, 1); if (g < PREK) wl[g] = kv; }
              } else {
                int p = atomicAdd(&lbc, 1);
                if (p < LCAP) lbnd[p] = kv;
                else { int g = atomicAdd(cb, 1); if (g < BCAP) bl[g] = kv; }
              }
            }
          }
        }
      }
    }
  }
  __syncthreads();
  flush_list(lwin, lwc, LCAP, cw, wl, PREK);
  flush_list(lbnd, lbc, LCAP, cb, bl, BCAP);
}

// ---------------- resolve boundary bin: pick exactly T more ----------------
// T = PREK - (#winners from gather). Refine on score bits [3,17) (8-ULP sub-bins);
// ties list sorts by FULL u64 key (score low bits then smaller idx) => exact.
__global__ void resolve_k(const u64* __restrict__ boundary,
                          int* __restrict__ cnt, u64* __restrict__ winners) {
  const int img = blockIdx.x;
  const int cw_pre = cnt[img * 64];
  const int T = PREK - cw_pre;
  int bc = cnt[img * 64 + 32];
  if (bc > BCAP) bc = BCAP;
  if (T <= 0 || bc <= 0) return;
  const u64* bnd = boundary + (size_t)img * BCAP;
  u64* wl = winners + (size_t)img * PREK;
  int* cw = &cnt[img * 64];

  __shared__ u32 h2[16384];
  __shared__ u32 lsum[256];
  __shared__ u32 above[256];
  __shared__ u32 s_total;
  __shared__ int sB2, sT2;
  __shared__ u64 ties[512];
  __shared__ int tcnt;
  __shared__ u64 lw2[PREK];
  __shared__ int lw2c;
  __shared__ int gbase_s;
  const int t = threadIdx.x;
  for (int i = t; i < 16384; i += 256) h2[i] = 0;
  if (t == 0) { tcnt = 0; sB2 = -1; sT2 = 0; lw2c = 0; }
  __syncthreads();
  for (int i = t; i < bc; i += 256) atomicAdd(&h2[(u32)(bnd[i] >> 35) & 0x3FFFu], 1u);
  __syncthreads();
  u32 s = 0;
  for (int j = 0; j < 64; ++j) s += h2[t * 64 + j];
  lsum[t] = s;
  __syncthreads();
  if (t == 0) {
    u32 acc = 0;
    for (int i = 255; i >= 0; --i) { above[i] = acc; acc += lsum[i]; }
    s_total = acc;
  }
  __syncthreads();
  if ((int)s_total > T) {
    if (above[t] < (u32)T && above[t] + lsum[t] >= (u32)T) {
      u32 cum = above[t];
      for (int j = 63; j >= 0; --j) {
        u32 hv = h2[t * 64 + j];
        cum += hv;
        if (cum >= (u32)T) { sB2 = t * 64 + j; sT2 = (int)((u32)T - (cum - hv)); break; }
      }
    }
  }
  __syncthreads();
  const int B2 = sB2, T2 = sT2;
  for (int i = t; i < bc; i += 256) {
    u64 e = bnd[i];
    int low = (int)((u32)(e >> 35) & 0x3FFFu);
    if (low > B2) {
      int p = atomicAdd(&lw2c, 1);
      if (p < PREK) lw2[p] = e;
    } else if (low == B2) {
      int tp = atomicAdd(&tcnt, 1);
      if (tp < 512) ties[tp] = e;
    }
  }
  __syncthreads();
  int n = lw2c < PREK ? lw2c : PREK;
  if (t == 0) gbase_s = n ? atomicAdd(cw, n) : 0;
  __syncthreads();
  for (int i = t; i < n; i += 256) {
    int pos = gbase_s + i;
    if (pos < PREK) wl[pos] = lw2[i];
  }
  __syncthreads();
  if (t == 0 && T2 > 0) {
    int tc = tcnt < 512 ? tcnt : 512;
    for (int k = 0; k < T2 && k < tc; ++k) {
      int bi = -1; u64 bk = 0;
      for (int i = 0; i < tc; ++i)
        if (ties[i] > bk) { bk = ties[i]; bi = i; }  // same score => larger ~idx = smaller idx first
      if (bi < 0) break;
      ties[bi] = 0;
      int pos = atomicAdd(cw, 1);
      if (pos < PREK) wl[pos] = bk;
    }
  }
}

// ---------------- rank, split j-dimension: partial ranks (plain stores, no atomics) ----------------
__global__ __launch_bounds__(256) void rank_part_k(const u64* __restrict__ winners,
                                                   const int* __restrict__ cnt,
                                                   int* __restrict__ part) {
  __shared__ u64 lk[RJW];
  const int img = blockIdx.y;
  const int kc = blockIdx.x >> 2;       // 16 key-chunks of 256
  const int jc = blockIdx.x & 3;        // 4 j-chunks of 1024
  const int t = threadIdx.x;
  int wc = cnt[img * 64]; if (wc > PREK) wc = PREK;
  const u64* wl = winners + (size_t)img * PREK;
  for (int i = t; i < RJW; i += 256) {
    const int gj = jc * RJW + i;
    lk[i] = (gj < wc) ? wl[gj] : pad_key(gj);
  }
  __syncthreads();
  const int ki_idx = kc * 256 + t;
  const u64 ki = (ki_idx < wc) ? wl[ki_idx] : pad_key(ki_idx);
  int rank = 0;
#pragma unroll 8
  for (int j = 0; j < RJW; ++j) rank += (lk[j] > ki) ? 1 : 0;
  part[(((size_t)img * RJC) + jc) * PREK + ki_idx] = rank;
}

// ---------------- rank scatter: sum partials, write sorted arrays ----------------
__global__ __launch_bounds__(256) void rank_scatter_k(const u64* __restrict__ winners,
                                              const int* __restrict__ cnt,
                                              const int* __restrict__ part,
                                              const float4* __restrict__ boxes,
                                              u64* __restrict__ skey,
                                              float4* __restrict__ sobox,
                                              float* __restrict__ sarea) {
  const int img = blockIdx.y;
  const int i = blockIdx.x * 256 + threadIdx.x;
  int wc = cnt[img * 64]; if (wc > PREK) wc = PREK;
  const u64* wl = winners + (size_t)img * PREK;
  const u64 ki = (i < wc) ? wl[i] : pad_key(i);
  const int* pb = part + (size_t)img * RJC * PREK + i;
  int rank = pb[0] + pb[PREK] + pb[2 * PREK] + pb[3 * PREK];
  skey[(size_t)img * PREK + rank] = ki;
  if (i < wc) {
    u32 ridx = ~(u32)ki;
    int c = (int)(ridx % NCLS);
    int bi = (int)(ridx / NCLS);
    float4 b = boxes[(size_t)img * NBOX + bi];
    float off = 4096.0f * (float)c;
    float4 ob = make_float4(b.x + off, b.y + off, b.z + off, b.w + off);
    sobox[(size_t)img * PREK + rank] = ob;
    sarea[(size_t)img * PREK + rank] = (ob.z - ob.x) * (ob.w - ob.y);
  } else {
    sobox[(size_t)img * PREK + rank] = make_float4(0.f, 0.f, 0.f, 0.f);
    sarea[(size_t)img * PREK + rank] = 0.f;
  }
}

// ---------------- sorted-scan greedy NMS: ballot class-match + bit-iterated pairs ----------------
__global__ __launch_bounds__(64) void scan_nms_k(const u64* __restrict__ skey,
                                                 const float4* __restrict__ sobox,
                                                 const float* __restrict__ sarea,
                                                 float* __restrict__ out) {
  __shared__ float4 bxc[NCLS][BKCAP];
  __shared__ float  arc[NCLS][BKCAP];
  __shared__ int    cntc[NCLS];
  __shared__ float4 bxa[TOPK];
  __shared__ float  ara[TOPK];
  __shared__ float4 bxh[HCAP];
  __shared__ float  arh[HCAP];
  __shared__ int    nhuge_s;
  __shared__ float4 chb[64];
  __shared__ float  cha[64];
  const int img = blockIdx.x;
  const int lane = threadIdx.x;
  float* orow = out + (size_t)img * (TOPK * 6);
  for (int i = lane; i < TOPK * 6; i += 64) orow[i] = 0.f;
  for (int i = lane; i < NCLS; i += 64) cntc[i] = 0;
  if (lane == 0) nhuge_s = 0;
  const u64* K = skey + (size_t)img * PREK;
  const float4* Bp = sobox + (size_t)img * PREK;
  const float* Ap = sarea + (size_t)img * PREK;
  int nsel = 0;
  u64 kj = K[lane];
  float4 ob = Bp[lane];
  float ar = Ap[lane];
  for (int chunk = 0; chunk < PREK / 64 && nsel < TOPK; ++chunk) {
    u64 kj_n = 0ull; float4 ob_n = make_float4(0.f, 0.f, 0.f, 0.f); float ar_n = 0.f;
    if (chunk + 1 < PREK / 64) {
      const int jn = (chunk + 1) * 64 + lane;
      kj_n = K[jn]; ob_n = Bp[jn]; ar_n = Ap[jn];
    }
    const float score = __uint_as_float((u32)(kj >> 32));
    bool alive = (score > SCORE_TH);
    if (__ballot(alive) == 0ull) break;   // sorted: nothing below passes either
    const u32 ridx = ~(u32)kj;
    const int myc = (int)(ridx % NCLS);
    const bool huge = (ob.z - ob.x > HUGE_TH) || (ob.w - ob.y > HUGE_TH);
    chb[lane] = ob; cha[lane] = ar;   // single wave: no barrier needed

    // 7-ballot class-match matrix
    u64 mm = ~0ull;
#pragma unroll
    for (int k = 0; k < 7; ++k) {
      const u64 bk = __ballot(((myc >> k) & 1) != 0);
      mm &= (((myc >> k) & 1) != 0) ? bk : ~bk;
    }
    const u64 hb = __ballot(huge);

    // phase 1a: same-class bucket walk (divergent; n<=8)
    {
      const int n0 = cntc[myc];
      const int n = n0 < BKCAP ? n0 : BKCAP;
      for (int k = 0; k < n && alive; ++k) {
        const float4 b0 = bxc[myc][k]; const float a0 = arc[myc][k];
        float xx1 = fmaxf(b0.x, ob.x), yy1 = fmaxf(b0.y, ob.y);
        float xx2 = fminf(b0.z, ob.z), yy2 = fminf(b0.w, ob.w);
        float inter = fmaxf(xx2 - xx1, 0.f) * fmaxf(yy2 - yy1, 0.f);
        float iou = inter / (a0 + ar - inter + 1e-9f);
        if (iou > IOU_TH) alive = false;
      }
    }
    // phase 1b: vs huge selected
    {
      const int nh = nhuge_s;
      for (int k = 0; k < nh; ++k) {
        if (alive) {
          const float4 b0 = bxh[k]; const float a0 = arh[k];
          float xx1 = fmaxf(b0.x, ob.x), yy1 = fmaxf(b0.y, ob.y);
          float xx2 = fminf(b0.z, ob.z), yy2 = fminf(b0.w, ob.w);
          float inter = fmaxf(xx2 - xx1, 0.f) * fmaxf(yy2 - yy1, 0.f);
          float iou = inter / (a0 + ar - inter + 1e-9f);
          if (iou > IOU_TH) alive = false;
        }
      }
    }
    // phase 1c: huge candidates vs ALL selected (rare)
    if (__ballot(alive && huge) != 0ull) {
      const int na = nsel;
      for (int k = 0; k < na; ++k) {
        if (alive && huge) {
          const float4 b0 = bxa[k]; const float a0 = ara[k];
          float xx1 = fmaxf(b0.x, ob.x), yy1 = fmaxf(b0.y, ob.y);
          float xx2 = fminf(b0.z, ob.z), yy2 = fminf(b0.w, ob.w);
          float inter = fmaxf(xx2 - xx1, 0.f) * fmaxf(yy2 - yy1, 0.f);
          float iou = inter / (a0 + ar - inter + 1e-9f);
          if (iou > IOU_TH) alive = false;
        }
      }
    }
    // in-chunk suppression: same-class / huge pairs among alive lanes
    const u64 amask = __ballot(alive);
    const u64 below = (1ull << lane) - 1ull;
    u64 tm = alive ? ((mm | hb | (huge ? ~0ull : 0ull)) & below & amask) : 0ull;
    u64 sup = 0ull;
    while (tm) {
      const int tb = (int)__builtin_ctzll(tm);
      tm &= tm - 1ull;
      const float4 bj = chb[tb];
      const float aj = cha[tb];
      float xx1 = fmaxf(bj.x, ob.x), yy1 = fmaxf(bj.y, ob.y);
      float xx2 = fminf(bj.z, ob.z), yy2 = fminf(bj.w, ob.w);
      float inter = fmaxf(xx2 - xx1, 0.f) * fmaxf(yy2 - yy1, 0.f);
      float iou = inter / (aj + ar - inter + 1e-9f);
      if (iou > IOU_TH) sup |= (1ull << tb);
    }
    // scalar greedy sweep
    u64 rem = amask;
    u64 selbits = 0ull;
    while (rem != 0ull && nsel + (int)__popcll(selbits) < TOPK) {
      const int b = __builtin_ctzll(rem);
      selbits |= (1ull << b);
      rem &= ~(1ull << b);
      const u64 colb = __ballot((sup >> b) & 1ull);
      rem &= ~colb;
    }
    // parallel commit
    const bool selme = (selbits >> lane) & 1ull;
    if (selme) {
      const int slot = nsel + (int)__popcll(selbits & ((1ull << lane) - 1ull));
      bxa[slot] = ob; ara[slot] = ar;
      if (!huge) {
        int cc = atomicAdd(&cntc[myc], 1);
        if (cc < BKCAP) { bxc[myc][cc] = ob; arc[myc][cc] = ar; }
        else { int hn = atomicAdd(&nhuge_s, 1); if (hn < HCAP) { bxh[hn] = ob; arh[hn] = ar; } }
      } else {
        int hn = atomicAdd(&nhuge_s, 1);
        if (hn < HCAP) { bxh[hn] = ob; arh[hn] = ar; }
      }
      const float off = 4096.0f * (float)myc;
      orow[slot * 6 + 0] = ob.x - off;
      orow[slot * 6 + 1] = ob.y - off;
      orow[slot * 6 + 2] = ob.z - off;
      orow[slot * 6 + 3] = ob.w - off;
      orow[slot * 6 + 4] = (float)myc;
      orow[slot * 6 + 5] = score;
    }
    nsel += (int)__popcll(selbits);
    kj = kj_n; ob = ob_n; ar = ar_n;
  }
}

extern "C" void kernel_launch(void* const* d_in, const int* in_sizes, int n_in,
                              void* d_out, int out_size, void* d_ws, size_t ws_size,
                              hipStream_t stream) {
  const float* in0 = (const float*)d_in[0];
  const float* in1 = (const float*)d_in[5];
  const float* in2 = (const float*)d_in[10];
  char* ws = (char*)d_ws;
  u32* hist = (u32*)(ws + HIST_OFF);
  int* cnt = (int*)(ws + CNT_OFF);
  u64* winners = (u64*)(ws + WIN_OFF);
  u64* boundary = (u64*)(ws + BND_OFF);
  int* part = (int*)(ws + PART_OFF);   // overlays boundary (safe: sequential kernels)
  float4* boxes = (float4*)(ws + BOX_OFF);
  u64* skey = (u64*)(ws + SKEY_OFF);
  float4* sobox = (float4*)(ws + SOBOX_OFF);
  float* sarea = (float*)(ws + SAREA_OFF);
  float* out = (float*)d_out;

  init_k<<<(ZERO_BYTES / 16 + 255) / 256, 256, 0, stream>>>((uint4*)ws);

  decode_hist_all<<<dim3(27, 8, DNCH), 256, 0, stream>>>(in0, in1, in2, boxes, hist);

  gather_all<<<dim3(27, 8, GNCH), 256, 0, stream>>>(in0, in1, in2, hist, cnt, winners, boundary);

  resolve_k<<<8, 256, 0, stream>>>(boundary, cnt, winners);

  rank_part_k<<<dim3(64, 8), 256, 0, stream>>>(winners, cnt, part);
  rank_scatter_k<<<dim3(16, 8), 256, 0, stream>>>(winners, cnt, part, boxes, skey, sobox, sarea);
  scan_nms_k<<<8, 64, 0, stream>>>(skey, sobox, sarea, out);
}